// Round 8
// baseline (170.759 us; speedup 1.0000x reference)
//
#include <hip/hip_runtime.h>

#define NB 4096
#define MM 128
#define NN 96
#define LL 20

#define SLOT_WORDS 9312        // per-batch ws slot: 9216 frag u32 + 96 hty f32
#define HTP_STRIDE 68          // staging row stride (u32): 16B-aligned octets, 2-way read banks

typedef __attribute__((ext_vector_type(8))) short bf16x8;
typedef __attribute__((ext_vector_type(4))) float f32x4;
typedef __attribute__((ext_vector_type(4))) unsigned int u32x4;

#define SEL_HI 0x07060302u
#define SEL_LO 0x05040100u

__device__ __forceinline__ unsigned bf16_rne(float f) {
    unsigned u = __float_as_uint(f);
    return (u + 0x7fffu + ((u >> 16) & 1u)) >> 16;
}
__device__ __forceinline__ unsigned pack_hl(float v) {
    unsigned hi = bf16_rne(v);
    unsigned lo = bf16_rne(v - __uint_as_float(hi << 16));
    return (hi << 16) | (lo & 0xffffu);
}
__device__ __forceinline__ bf16x8 mk8(unsigned a, unsigned b, unsigned c, unsigned d) {
    u32x4 t; t[0] = a; t[1] = b; t[2] = c; t[3] = d;
    return __builtin_bit_cast(bf16x8, t);
}
struct PairHL { bf16x8 hi, lo; };
__device__ __forceinline__ PairHL unpack_pair(u32x4 q0, u32x4 q1) {
    PairHL p;
    p.hi = mk8(__builtin_amdgcn_perm(q0[1], q0[0], SEL_HI), __builtin_amdgcn_perm(q0[3], q0[2], SEL_HI),
               __builtin_amdgcn_perm(q1[1], q1[0], SEL_HI), __builtin_amdgcn_perm(q1[3], q1[2], SEL_HI));
    p.lo = mk8(__builtin_amdgcn_perm(q0[1], q0[0], SEL_LO), __builtin_amdgcn_perm(q0[3], q0[2], SEL_LO),
               __builtin_amdgcn_perm(q1[1], q1[0], SEL_LO), __builtin_amdgcn_perm(q1[3], q1[2], SEL_LO));
    return p;
}

// ===================== Kernel A: HTH+HTy per batch, frag-order output =====================
// Frag layout (matches kernel B's A-frag reads, derived from R6/R7-verified layouts):
//   slot[((I*3+kk)*64 + lane)*8 + u] = packed(hi|lo) HTH[I*16 + (lane&15)][kk*32 + (lane>>4)*8 + u]
__global__ __launch_bounds__(256) __attribute__((amdgpu_waves_per_eu(3)))
void hth_kernel(const float* __restrict__ H, const float* __restrict__ y,
                unsigned* __restrict__ ws, int b0)
{
    __shared__ unsigned U[112 * HTP_STRIDE];   // 30.5 KB: Ht packed, row c = H col c, row 96 = y
    const int b    = b0 + blockIdx.x;
    const int tid  = threadIdx.x;
    const int lane = tid & 63;
    const int wid  = tid >> 6;
    const int m15  = lane & 15;
    const int g4   = lane >> 4;
    const int nJ   = (wid == 3) ? 1 : 2;       // J-tiles {wid, wid+4} (J=6 holds the y column)
    const int r16  = tid >> 2;                 // H row within k-half
    const int cg4  = tid & 3;                  // 24-col group

    f32x4 acc[2][6];
    #pragma unroll
    for (int j = 0; j < 2; ++j)
        #pragma unroll
        for (int i = 0; i < 6; ++i)
            #pragma unroll
            for (int r = 0; r < 4; ++r) acc[j][i][r] = 0.f;

    // prefetch BOTH k-halves up-front (HBM latency overlaps half-0 compute)
    const float* src = H + (size_t)b * (MM * NN) + (size_t)r16 * NN + cg4 * 24;
    float4 v0[6], v1[6];
    #pragma unroll
    for (int i = 0; i < 6; ++i) {
        v0[i] = *(const float4*)(src + 4 * i);
        v1[i] = *(const float4*)(src + 64 * NN + 4 * i);
    }
    float ya = 0.f, yb = 0.f;
    if (tid < 64) {
        ya = y[(size_t)b * MM + tid];
        yb = y[(size_t)b * MM + 64 + tid];
    }

    for (int kh = 0; kh < 2; ++kh) {
        if (kh) __syncthreads();               // half-0 frag reads complete
        #pragma unroll
        for (int i = 0; i < 6; ++i) {
            const float4 vv = kh ? v1[i] : v0[i];
            const int c = cg4 * 24 + 4 * i;
            U[(c + 0) * HTP_STRIDE + r16] = pack_hl(vv.x);
            U[(c + 1) * HTP_STRIDE + r16] = pack_hl(vv.y);
            U[(c + 2) * HTP_STRIDE + r16] = pack_hl(vv.z);
            U[(c + 3) * HTP_STRIDE + r16] = pack_hl(vv.w);
        }
        if (tid < 64) U[96 * HTP_STRIDE + tid] = pack_hl(kh ? yb : ya);
        __syncthreads();

        #pragma unroll
        for (int kk = 0; kk < 2; ++kk) {
            const int kbase = kk * 32 + g4 * 8;
            bf16x8 Bh[2], Bl[2];
            #pragma unroll
            for (int j = 0; j < 2; ++j) {
                if (j < nJ) {
                    const int base = ((wid + 4 * j) * 16 + m15) * HTP_STRIDE + kbase;
                    u32x4 q0 = *(const u32x4*)&U[base];
                    u32x4 q1 = *(const u32x4*)&U[base + 4];
                    PairHL p = unpack_pair(q0, q1);
                    Bh[j] = p.hi; Bl[j] = p.lo;
                }
            }
            #pragma unroll
            for (int I = 0; I < 6; ++I) {
                const int base = (I * 16 + m15) * HTP_STRIDE + kbase;
                u32x4 q0 = *(const u32x4*)&U[base];
                u32x4 q1 = *(const u32x4*)&U[base + 4];
                PairHL A = unpack_pair(q0, q1);
                #pragma unroll
                for (int j = 0; j < 2; ++j) {
                    if (j < nJ) {
                        acc[j][I] = __builtin_amdgcn_mfma_f32_16x16x32_bf16(A.hi, Bh[j], acc[j][I], 0, 0, 0);
                        acc[j][I] = __builtin_amdgcn_mfma_f32_16x16x32_bf16(A.hi, Bl[j], acc[j][I], 0, 0, 0);
                        acc[j][I] = __builtin_amdgcn_mfma_f32_16x16x32_bf16(A.lo, Bh[j], acc[j][I], 0, 0, 0);
                    }
                }
            }
        }
    }

    // C-write straight to global ws in frag order (C layout m89-verified: col=J*16+m15, row=I*16+g4*4+r)
    unsigned* slot = ws + (size_t)blockIdx.x * SLOT_WORDS;
    float* htyp = (float*)(slot + 9216);
    #pragma unroll
    for (int j = 0; j < 2; ++j) {
        if (j < nJ) {
            const int col = (wid + 4 * j) * 16 + m15;
            #pragma unroll
            for (int I = 0; I < 6; ++I) {
                #pragma unroll
                for (int r = 0; r < 4; ++r) {
                    const int row = I * 16 + g4 * 4 + r;
                    if (col < 96) {
                        const int w = ((I * 3 + (col >> 5)) * 64 + ((col >> 3) & 3) * 16 + (row & 15)) * 8 + (col & 7);
                        slot[w] = pack_hl(acc[j][I][r]);
                    } else if (col == 96) {
                        htyp[row] = acc[j][I][r];
                    }
                }
            }
        }
    }
}

// ===================== Kernel B: wave-autonomous FISTA, ZERO barriers =====================
__global__ __launch_bounds__(256) __attribute__((amdgpu_waves_per_eu(2)))
void fista_kernel(const unsigned* __restrict__ ws,
                  const float* __restrict__ x_ini,
                  const float* __restrict__ xt,
                  const float* __restrict__ grad_ss,
                  const float* __restrict__ extra_ss,
                  const float* __restrict__ gamma1,
                  float* __restrict__ out, int b0)
{
    __shared__ unsigned yxP[4][NN];            // wave-private packed yx
    const int tid  = threadIdx.x;
    const int lane = tid & 63;
    const int wid  = tid >> 6;
    const int m15  = lane & 15;
    const int g4   = lane >> 4;
    const int lb   = blockIdx.x * 4 + wid;     // local batch (one per wave)
    const int b    = b0 + lb;
    const unsigned* slot = ws + (size_t)lb * SLOT_WORDS;

    // ---- A-frags: coalesced (2KB/instruction), once ----
    bf16x8 ahi[6][3], alo[6][3];
    #pragma unroll
    for (int I = 0; I < 6; ++I)
        #pragma unroll
        for (int kk = 0; kk < 3; ++kk) {
            const u32x4* p = (const u32x4*)(slot + ((size_t)(I * 3 + kk) * 64 + lane) * 8);
            PairHL A = unpack_pair(p[0], p[1]);
            ahi[I][kk] = A.hi; alo[I][kk] = A.lo;
        }

    // ---- writer-lane state: lane (m15<6, g4) owns rows rb..rb+3, rb = m15*16+g4*4 ----
    const int  rb = m15 * 16 + g4 * 4;
    const bool wr = (m15 < 6);
    float yx4[4] = {0,0,0,0}, xc4[4] = {0,0,0,0}, hty4[4] = {0,0,0,0};
    if (wr) {
        float4 xi = *(const float4*)(x_ini + (size_t)b * NN + rb);
        float4 ht = *(const float4*)((const float*)(slot + 9216) + rb);
        yx4[0] = xi.x; yx4[1] = xi.y; yx4[2] = xi.z; yx4[3] = xi.w;
        xc4[0] = xi.x; xc4[1] = xi.y; xc4[2] = xi.z; xc4[3] = xi.w;
        hty4[0] = ht.x; hty4[1] = ht.y; hty4[2] = ht.z; hty4[3] = ht.w;
        u32x4 pk;
        #pragma unroll
        for (int r = 0; r < 4; ++r) pk[r] = pack_hl(yx4[r]);
        *(u32x4*)&yxP[wid][rb] = pk;
    }
    __builtin_amdgcn_sched_barrier(0);         // publish before first read (same-wave lgkmcnt order)

    for (int t = 0; t < LL; ++t) {
        // broadcast B-frags from wave-private yx (same addr per 16-lane group: conflict-free)
        bf16x8 bhi[3], blo[3];
        #pragma unroll
        for (int kk = 0; kk < 3; ++kk) {
            u32x4 q0 = *(const u32x4*)&yxP[wid][kk * 32 + g4 * 8];
            u32x4 q1 = *(const u32x4*)&yxP[wid][kk * 32 + g4 * 8 + 4];
            PairHL p = unpack_pair(q0, q1);
            bhi[kk] = p.hi; blo[kk] = p.lo;
        }
        f32x4 a0 = {0,0,0,0}, a1 = {0,0,0,0}, a2 = {0,0,0,0}, a3 = {0,0,0,0}, a4 = {0,0,0,0}, a5 = {0,0,0,0};
        #pragma unroll
        for (int kk = 0; kk < 3; ++kk) {
            a0 = __builtin_amdgcn_mfma_f32_16x16x32_bf16(ahi[0][kk], bhi[kk], a0, 0, 0, 0);
            a0 = __builtin_amdgcn_mfma_f32_16x16x32_bf16(ahi[0][kk], blo[kk], a0, 0, 0, 0);
            a0 = __builtin_amdgcn_mfma_f32_16x16x32_bf16(alo[0][kk], bhi[kk], a0, 0, 0, 0);
            a1 = __builtin_amdgcn_mfma_f32_16x16x32_bf16(ahi[1][kk], bhi[kk], a1, 0, 0, 0);
            a1 = __builtin_amdgcn_mfma_f32_16x16x32_bf16(ahi[1][kk], blo[kk], a1, 0, 0, 0);
            a1 = __builtin_amdgcn_mfma_f32_16x16x32_bf16(alo[1][kk], bhi[kk], a1, 0, 0, 0);
            a2 = __builtin_amdgcn_mfma_f32_16x16x32_bf16(ahi[2][kk], bhi[kk], a2, 0, 0, 0);
            a2 = __builtin_amdgcn_mfma_f32_16x16x32_bf16(ahi[2][kk], blo[kk], a2, 0, 0, 0);
            a2 = __builtin_amdgcn_mfma_f32_16x16x32_bf16(alo[2][kk], bhi[kk], a2, 0, 0, 0);
            a3 = __builtin_amdgcn_mfma_f32_16x16x32_bf16(ahi[3][kk], bhi[kk], a3, 0, 0, 0);
            a3 = __builtin_amdgcn_mfma_f32_16x16x32_bf16(ahi[3][kk], blo[kk], a3, 0, 0, 0);
            a3 = __builtin_amdgcn_mfma_f32_16x16x32_bf16(alo[3][kk], bhi[kk], a3, 0, 0, 0);
            a4 = __builtin_amdgcn_mfma_f32_16x16x32_bf16(ahi[4][kk], bhi[kk], a4, 0, 0, 0);
            a4 = __builtin_amdgcn_mfma_f32_16x16x32_bf16(ahi[4][kk], blo[kk], a4, 0, 0, 0);
            a4 = __builtin_amdgcn_mfma_f32_16x16x32_bf16(alo[4][kk], bhi[kk], a4, 0, 0, 0);
            a5 = __builtin_amdgcn_mfma_f32_16x16x32_bf16(ahi[5][kk], bhi[kk], a5, 0, 0, 0);
            a5 = __builtin_amdgcn_mfma_f32_16x16x32_bf16(ahi[5][kk], blo[kk], a5, 0, 0, 0);
            a5 = __builtin_amdgcn_mfma_f32_16x16x32_bf16(alo[5][kk], bhi[kk], a5, 0, 0, 0);
        }
        // this lane's w values: acc[m15][r] (static select chain, no runtime indexing)
        f32x4 am = a0;
        am = (m15 == 1) ? a1 : am;
        am = (m15 == 2) ? a2 : am;
        am = (m15 == 3) ? a3 : am;
        am = (m15 == 4) ? a4 : am;
        am = (m15 == 5) ? a5 : am;

        const float gs = grad_ss[t], es = extra_ss[t], gm = gamma1[t];
        if (wr) {
            u32x4 pk;
            #pragma unroll
            for (int r = 0; r < 4; ++r) {
                float xb  = fmaf(-2.0f * gs, am[r] - hty4[r], yx4[r]);
                float cen = 2.0f * fminf(fmaxf(rintf(xb * 0.5f), -1.0f), 1.0f);
                float z   = gm * (xb - cen);
                float e   = __expf(-z);
                float ply = fmaf(2.0f, __builtin_amdgcn_rcpf(1.0f + e), -1.0f);
                float yxn = fmaf(es, ply - xc4[r], ply);
                xc4[r] = ply;
                yx4[r] = yxn;
                pk[r]  = pack_hl(yxn);
            }
            if (t + 1 < LL) *(u32x4*)&yxP[wid][rb] = pk;
        }
        __builtin_amdgcn_sched_barrier(0);     // keep write-before-next-read order
    }

    // ---- epilogue: x out + loss ----
    float part = 0.f;
    if (wr) {
        float4 xo, xr;
        xo.x = xc4[0]; xo.y = xc4[1]; xo.z = xc4[2]; xo.w = xc4[3];
        *(float4*)(out + (size_t)b * NN + rb) = xo;
        xr = *(const float4*)(xt + (size_t)b * NN + rb);
        float d0 = xc4[0] - xr.x, d1 = xc4[1] - xr.y, d2 = xc4[2] - xr.z, d3 = xc4[3] - xr.w;
        part = (d0 * d0 + d1 * d1) + (d2 * d2 + d3 * d3);
    }
    #pragma unroll
    for (int m = 1; m < 64; m <<= 1) part += __shfl_xor(part, m, 64);
    if (lane == 0) atomicAdd(out + (size_t)NB * NN, part);
}

extern "C" void kernel_launch(void* const* d_in, const int* in_sizes, int n_in,
                              void* d_out, int out_size, void* d_ws, size_t ws_size,
                              hipStream_t stream) {
    const float* x_ini    = (const float*)d_in[0];
    const float* y        = (const float*)d_in[1];
    const float* H        = (const float*)d_in[2];
    const float* xt       = (const float*)d_in[3];
    const float* grad_ss  = (const float*)d_in[4];
    const float* extra_ss = (const float*)d_in[5];
    const float* gamma1   = (const float*)d_in[6];
    float* out = (float*)d_out;
    unsigned* ws = (unsigned*)d_ws;

    int CB = (int)(ws_size / (SLOT_WORDS * 4));   // batches per chunk that fit in ws
    if (CB > NB) CB = NB;
    CB &= ~3;
    if (CB < 4) CB = 4;                            // (assumes ws >= 149 KB)

    hipMemsetAsync(out + (size_t)NB * NN, 0, sizeof(float), stream);
    for (int b0 = 0; b0 < NB; b0 += CB) {
        int n = NB - b0; if (n > CB) n = CB;
        hth_kernel<<<n, 256, 0, stream>>>(H, y, ws, b0);
        fista_kernel<<<n / 4, 256, 0, stream>>>(ws, x_ini, xt, grad_ss, extra_ss, gamma1, out, b0);
    }
}

// Round 9
// 96.234 us; speedup vs baseline: 1.7744x; 1.7744x over previous
//
#include <hip/hip_runtime.h>

#define NB 4096
#define MM 128
#define NN 96
#define LL 20

typedef __attribute__((ext_vector_type(8))) short bf16x8;
typedef __attribute__((ext_vector_type(4))) float f32x4;
typedef __attribute__((ext_vector_type(4))) unsigned int u32x4;

#define UT_STRIDE 72   // u16 per row: 144B, b128-aligned, 2-way write banks

__device__ __forceinline__ unsigned short rne16(float f) {
    unsigned u = __float_as_uint(f);
    return (unsigned short)((u + 0x7fffu + ((u >> 16) & 1u)) >> 16);
}
__device__ __forceinline__ unsigned pack2(float a, float b) {
    return (unsigned)rne16(a) | ((unsigned)rne16(b) << 16);
}
__device__ __forceinline__ float bperm_f(int srcB, float v) {
    return __int_as_float(__builtin_amdgcn_ds_bpermute(srcB, __float_as_int(v)));
}

// One wave = one batch. 64-thread blocks, grid = 4096. No inter-wave coupling,
// no workspace traffic: HTH lives only in accs -> in-register transpose -> frags.
__global__ __launch_bounds__(64) __attribute__((amdgpu_waves_per_eu(2)))
void pg_kernel(const float* __restrict__ x_ini,
               const float* __restrict__ y,
               const float* __restrict__ H,
               const float* __restrict__ xt,
               const float* __restrict__ grad_ss,
               const float* __restrict__ extra_ss,
               const float* __restrict__ gamma1,
               float* __restrict__ out)
{
    __shared__ __align__(16) unsigned short Ut[112 * UT_STRIDE]; // H^T bf16, row c = H col c; row 96 = y
    __shared__ __align__(16) unsigned yxL[48];                   // packed bf16 yx
    __shared__ float par[3][LL];

    const int b    = blockIdx.x;
    const int lane = threadIdx.x;
    const int m15  = lane & 15;
    const int g4   = lane >> 4;

    if (lane < LL) {
        par[0][lane] = grad_ss[lane];
        par[1][lane] = extra_ss[lane];
        par[2][lane] = gamma1[lane];
    }
    // zero garbage rows 97..111 once (J=6 frag reads touch them)
    {
        unsigned* U32 = (unsigned*)Ut;
        #pragma unroll
        for (int i = 97 * (UT_STRIDE / 2) + lane; i < 112 * (UT_STRIDE / 2); i += 64)
            U32[i] = 0;
    }

    // ================= Phase A: HTH_ext = [H|y]^T [H|y], single-pass bf16 =================
    f32x4 acc[6][7];
    #pragma unroll
    for (int I = 0; I < 6; ++I)
        #pragma unroll
        for (int J = 0; J < 7; ++J)
            #pragma unroll
            for (int r = 0; r < 4; ++r) acc[I][J][r] = 0.f;

    const float* Hb = H + (size_t)b * (MM * NN);
    for (int kh = 0; kh < 2; ++kh) {
        if (kh) __syncthreads();               // kh=0 frag reads done before restage
        // stage: lane = H row (kh*64+lane), transpose-write 96 bf16 (2-way banks = free)
        const float* rsrc = Hb + (size_t)(kh * 64 + lane) * NN;
        #pragma unroll
        for (int ch = 0; ch < 4; ++ch) {
            float4 v[6];
            #pragma unroll
            for (int i = 0; i < 6; ++i) v[i] = *(const float4*)(rsrc + ch * 24 + 4 * i);
            #pragma unroll
            for (int i = 0; i < 6; ++i) {
                const int c = ch * 24 + 4 * i;
                Ut[(c + 0) * UT_STRIDE + lane] = rne16(v[i].x);
                Ut[(c + 1) * UT_STRIDE + lane] = rne16(v[i].y);
                Ut[(c + 2) * UT_STRIDE + lane] = rne16(v[i].z);
                Ut[(c + 3) * UT_STRIDE + lane] = rne16(v[i].w);
            }
        }
        Ut[96 * UT_STRIDE + lane] = rne16(y[(size_t)b * MM + kh * 64 + lane]);
        __syncthreads();

        #pragma unroll
        for (int s = 0; s < 2; ++s) {          // two K=32 steps per half
            bf16x8 fr[7];                      // A-frag == B-frag (HTH symmetric product)
            #pragma unroll
            for (int T = 0; T < 7; ++T)
                fr[T] = *(const bf16x8*)&Ut[(T * 16 + m15) * UT_STRIDE + s * 32 + g4 * 8];
            #pragma unroll
            for (int I = 0; I < 6; ++I)
                #pragma unroll
                for (int J = 0; J < 7; ++J)
                    acc[I][J] = __builtin_amdgcn_mfma_f32_16x16x32_bf16(fr[I], fr[J], acc[I][J], 0, 0, 0);
        }
    }

    // ============ Transition: acc (D-layout) -> phase-B A-frags via symmetry + quad bpermute ============
    // Needed: afr[I'][kk] = bf16 HTH[I'*16+m15][kk*32+g4*8+2p(+1)]  (u32 p)
    //       = HTH[c][I'*16+m15] = acc[2kk+(g4>>1)][I'] pair (p&1) at lane (m15, 2*(g4&1)+(p>>1)).
    unsigned pk[6][6][2];
    #pragma unroll
    for (int I = 0; I < 6; ++I)
        #pragma unroll
        for (int J = 0; J < 6; ++J) {
            pk[I][J][0] = pack2(acc[I][J][0], acc[I][J][1]);
            pk[I][J][1] = pack2(acc[I][J][2], acc[I][J][3]);
        }
    const int srcL[2] = { (m15 + 16 * (2 * (g4 & 1) + 0)) << 2,
                          (m15 + 16 * (2 * (g4 & 1) + 1)) << 2 };
    const bool hiHalf = (g4 >> 1) != 0;
    bf16x8 afr[6][3];
    #pragma unroll
    for (int Ip = 0; Ip < 6; ++Ip)
        #pragma unroll
        for (int kk = 0; kk < 3; ++kk) {
            u32x4 w;
            #pragma unroll
            for (int p = 0; p < 4; ++p) {
                int va = __builtin_amdgcn_ds_bpermute(srcL[p >> 1], (int)pk[2 * kk][Ip][p & 1]);
                int vb = __builtin_amdgcn_ds_bpermute(srcL[p >> 1], (int)pk[2 * kk + 1][Ip][p & 1]);
                w[p] = (unsigned)(hiHalf ? vb : va);
            }
            afr[Ip][kk] = __builtin_bit_cast(bf16x8, w);
        }
    // hty for writer rows: HTH_ext[row][96] = acc[I][6][r] col 0 -> at lane (0, g4)
    float hty4[4];
    {
        const int srcC = (16 * g4) << 2;
        #pragma unroll
        for (int r = 0; r < 4; ++r) {
            float v0 = bperm_f(srcC, acc[0][6][r]);
            float v1 = bperm_f(srcC, acc[1][6][r]);
            float v2 = bperm_f(srcC, acc[2][6][r]);
            float v3 = bperm_f(srcC, acc[3][6][r]);
            float v4 = bperm_f(srcC, acc[4][6][r]);
            float v5 = bperm_f(srcC, acc[5][6][r]);
            float s = v0;
            s = (m15 == 1) ? v1 : s;
            s = (m15 == 2) ? v2 : s;
            s = (m15 == 3) ? v3 : s;
            s = (m15 == 4) ? v4 : s;
            s = (m15 == 5) ? v5 : s;
            hty4[r] = s;
        }
    }

    // ================= Phase B: 20 iterations, wave-local =================
    const bool wr = (m15 < 6);
    const int  rb = m15 * 16 + g4 * 4;         // writer owns rows rb..rb+3
    float yx4[4] = {0, 0, 0, 0}, xc4[4] = {0, 0, 0, 0};
    if (wr) {
        float4 xi = *(const float4*)(x_ini + (size_t)b * NN + rb);
        yx4[0] = xi.x; yx4[1] = xi.y; yx4[2] = xi.z; yx4[3] = xi.w;
        xc4[0] = xi.x; xc4[1] = xi.y; xc4[2] = xi.z; xc4[3] = xi.w;
        yxL[(rb >> 1) + 0] = pack2(yx4[0], yx4[1]);
        yxL[(rb >> 1) + 1] = pack2(yx4[2], yx4[3]);
    }
    __syncthreads();

    for (int t = 0; t < LL; ++t) {
        bf16x8 bf[3];                          // broadcast yx k-slices
        #pragma unroll
        for (int kk = 0; kk < 3; ++kk)
            bf[kk] = *(const bf16x8*)&yxL[kk * 16 + g4 * 4];
        f32x4 aD[6];
        #pragma unroll
        for (int Ip = 0; Ip < 6; ++Ip)
            #pragma unroll
            for (int r = 0; r < 4; ++r) aD[Ip][r] = 0.f;
        #pragma unroll
        for (int kk = 0; kk < 3; ++kk)
            #pragma unroll
            for (int Ip = 0; Ip < 6; ++Ip)
                aD[Ip] = __builtin_amdgcn_mfma_f32_16x16x32_bf16(afr[Ip][kk], bf[kk], aD[Ip], 0, 0, 0);
        // lane's w values: aD[m15][r] = w[m15*16 + g4*4 + r] (static select chain)
        f32x4 am = aD[0];
        am = (m15 == 1) ? aD[1] : am;
        am = (m15 == 2) ? aD[2] : am;
        am = (m15 == 3) ? aD[3] : am;
        am = (m15 == 4) ? aD[4] : am;
        am = (m15 == 5) ? aD[5] : am;

        if (wr) {
            const float gs = par[0][t], es = par[1][t], gmv = par[2][t];
            #pragma unroll
            for (int r = 0; r < 4; ++r) {
                float xb  = fmaf(-2.0f * gs, am[r] - hty4[r], yx4[r]);
                float cen = 2.0f * fminf(fmaxf(rintf(xb * 0.5f), -1.0f), 1.0f);
                float z   = gmv * (xb - cen);
                float e   = __expf(-z);
                float ply = fmaf(2.0f, __builtin_amdgcn_rcpf(1.0f + e), -1.0f);
                float yxn = fmaf(es, ply - xc4[r], ply);
                xc4[r] = ply;
                yx4[r] = yxn;
            }
            if (t + 1 < LL) {
                yxL[(rb >> 1) + 0] = pack2(yx4[0], yx4[1]);
                yxL[(rb >> 1) + 1] = pack2(yx4[2], yx4[3]);
            }
        }
        __syncthreads();   // 1-wave block: just lgkmcnt ordering for yxL
    }

    // ================= epilogue =================
    float part = 0.f;
    if (wr) {
        float4 xo;
        xo.x = xc4[0]; xo.y = xc4[1]; xo.z = xc4[2]; xo.w = xc4[3];
        *(float4*)(out + (size_t)b * NN + rb) = xo;
        float4 xr = *(const float4*)(xt + (size_t)b * NN + rb);
        float d0 = xc4[0] - xr.x, d1 = xc4[1] - xr.y;
        float d2 = xc4[2] - xr.z, d3 = xc4[3] - xr.w;
        part = (d0 * d0 + d1 * d1) + (d2 * d2 + d3 * d3);
    }
    #pragma unroll
    for (int m = 1; m < 64; m <<= 1) part += __shfl_xor(part, m, 64);
    if (lane == 0) atomicAdd(out + (size_t)NB * NN, part);
}

extern "C" void kernel_launch(void* const* d_in, const int* in_sizes, int n_in,
                              void* d_out, int out_size, void* d_ws, size_t ws_size,
                              hipStream_t stream) {
    const float* x_ini    = (const float*)d_in[0];
    const float* y        = (const float*)d_in[1];
    const float* H        = (const float*)d_in[2];
    const float* xt       = (const float*)d_in[3];
    const float* grad_ss  = (const float*)d_in[4];
    const float* extra_ss = (const float*)d_in[5];
    const float* gamma1   = (const float*)d_in[6];
    float* out = (float*)d_out;

    hipMemsetAsync(out + (size_t)NB * NN, 0, sizeof(float), stream);
    pg_kernel<<<NB, 64, 0, stream>>>(x_ini, y, H, xt, grad_ss, extra_ss, gamma1, out);
}